// Round 4
// baseline (410.005 us; speedup 1.0000x reference)
//
#include <hip/hip_runtime.h>
#include <hip/hip_bf16.h>
#include <stdint.h>

#define EPSF 1e-5f

typedef __attribute__((ext_vector_type(8))) short short8;
typedef __attribute__((ext_vector_type(4))) float f32x4;

__device__ inline short f2bf(float f) {
    union { float f; unsigned u; } x; x.f = f;
    unsigned u = x.u;
    unsigned r = (u + 0x7FFFu + ((u >> 16) & 1u)) >> 16;  // round-to-nearest-even
    return (short)r;
}

__device__ inline f32x4 mfma16x16x32(short8 a, short8 b, f32x4 c) {
    return __builtin_amdgcn_mfma_f32_16x16x32_bf16(a, b, c, 0, 0, 0);
}

// ---------------------------------------------------------------------------
// BT-GEMM: C[M,N] = A[M,KP] * B[N,KP]^T   (A,B bf16-as-short, KP % 32 == 0)
// MODE 0: full-K, C = f32, += bias[col] if bias != nullptr
// MODE 1: split-K over blockIdx.z (uneven segments), partials to C + z*M*ldc
// Tile: 128x128, BK=32, 4 waves (2x2), each wave 64x64 via 4x4 MFMA frags.
// 2-buffer LDS pipeline (32 KB -> 5 blocks/CU): stage(t+1) issued right
// after the barrier at step t; vmcnt(0) at top of t+1 waits for a batch
// that has had a full step (~2000 cyc >> 900-cyc HBM) to land.
// 16B-block XOR swizzle applied on BOTH sides (global src + ds_read addr).
// ---------------------------------------------------------------------------
template <int MODE>
__global__ __launch_bounds__(256) void gemm_bt(
    const short* __restrict__ A, const short* __restrict__ B,
    float* __restrict__ C, int M, int N, int KP, int ldc,
    const float* __restrict__ bias)
{
    __shared__ alignas(16) short As[2][128 * 32];
    __shared__ alignas(16) short Bs[2][128 * 32];

    const int tid = threadIdx.x;
    const int l   = tid & 63;
    const int w   = tid >> 6;
    const int wr  = w >> 1, wc = w & 1;
    const int m0  = blockIdx.x * 128;
    const int n0  = blockIdx.y * 128;

    int k_beg = 0, k_end = KP;
    if (MODE == 1) {
        int steps = KP >> 5;
        long long z = blockIdx.z;
        int s0 = (int)(z * steps / gridDim.z);
        int s1 = (int)((z + 1) * steps / gridDim.z);
        k_beg = s0 << 5;
        k_end = s1 << 5;
    }

    // staging geometry: lane l stages 16B to linear LDS slot (row sr, blk l&3)
    // sourcing the LOGICAL block (l&3)^((sr>>1)&3) from global
    const int sr   = l >> 2;
    const int sc   = ((l & 3) ^ ((sr >> 1) & 3)) * 8;
    // read geometry (same XOR on the LDS side)
    const int lr   = l & 15;
    const int kg   = l >> 4;
    const int kswz = (kg ^ ((lr >> 1) & 3)) * 8;

    const short* gaBase = A + (size_t)(m0 + (w * 2) * 16 + sr) * KP + sc;
    int rB0 = n0 + (w * 2) * 16 + sr;      // B rows, clamped to stay in-bounds
    int rB1 = rB0 + 16;
    if (rB0 > N - 1) rB0 = N - 1;
    if (rB1 > N - 1) rB1 = N - 1;
    const short* gbBase0 = B + (size_t)rB0 * KP + sc;
    const short* gbBase1 = B + (size_t)rB1 * KP + sc;

    auto stage = [&](int buf, int k0) {
        const int g = w * 2;
        __builtin_amdgcn_global_load_lds(
            (const __attribute__((address_space(1))) void*)(gaBase + k0),
            (__attribute__((address_space(3))) void*)(&As[buf][g * 512]), 16, 0, 0);
        __builtin_amdgcn_global_load_lds(
            (const __attribute__((address_space(1))) void*)(gbBase0 + k0),
            (__attribute__((address_space(3))) void*)(&Bs[buf][g * 512]), 16, 0, 0);
        __builtin_amdgcn_global_load_lds(
            (const __attribute__((address_space(1))) void*)(gaBase + (size_t)16 * KP + k0),
            (__attribute__((address_space(3))) void*)(&As[buf][(g + 1) * 512]), 16, 0, 0);
        __builtin_amdgcn_global_load_lds(
            (const __attribute__((address_space(1))) void*)(gbBase1 + k0),
            (__attribute__((address_space(3))) void*)(&Bs[buf][(g + 1) * 512]), 16, 0, 0);
    };

    f32x4 acc[4][4] = {};

    const int nt = (k_end - k_beg) >> 5;
    stage(0, k_beg);

    int rd = 0;
    for (int t = 0; t < nt; ++t) {
        asm volatile("s_waitcnt vmcnt(0)" ::: "memory");
        __builtin_amdgcn_s_barrier();
        __builtin_amdgcn_sched_barrier(0);

        if (t + 1 < nt) stage(rd ^ 1, k_beg + ((t + 1) << 5));

        short8 af[4], bfr[4];
#pragma unroll
        for (int mi = 0; mi < 4; ++mi)
            af[mi] = *(const short8*)&As[rd][(wr * 64 + mi * 16 + lr) * 32 + kswz];
#pragma unroll
        for (int ni = 0; ni < 4; ++ni)
            bfr[ni] = *(const short8*)&Bs[rd][(wc * 64 + ni * 16 + lr) * 32 + kswz];
#pragma unroll
        for (int mi = 0; mi < 4; ++mi)
#pragma unroll
            for (int ni = 0; ni < 4; ++ni)
                acc[mi][ni] = mfma16x16x32(af[mi], bfr[ni], acc[mi][ni]);

        asm volatile("s_waitcnt lgkmcnt(0)" ::: "memory");
        rd ^= 1;
    }

    float* Cb = C;
    if (MODE == 1) Cb = C + (size_t)blockIdx.z * M * ldc;

#pragma unroll
    for (int ni = 0; ni < 4; ++ni) {
        int col = n0 + wc * 64 + ni * 16 + lr;
        if (col >= N) continue;
        float bv = (MODE == 0 && bias) ? bias[col] : 0.0f;
#pragma unroll
        for (int mi = 0; mi < 4; ++mi) {
            int row0 = m0 + wr * 64 + mi * 16 + kg * 4;
#pragma unroll
            for (int r = 0; r < 4; ++r)
                Cb[(size_t)(row0 + r) * ldc + col] = acc[mi][ni][r] + bv;
        }
    }
}

// ---------------------------------------------------------------------------
// fused gathers: entity row + BN0 -> f32 x[2048,400]; relation row -> bf16
// padded to 416 cols
// ---------------------------------------------------------------------------
__global__ void gather_fused(const float* __restrict__ E, const int* __restrict__ eidx,
                             const float* __restrict__ R, const int* __restrict__ ridx,
                             const float* g, const float* bb, const float* m,
                             const float* v, float* __restrict__ xout,
                             short* __restrict__ rout)
{
    int b = blockIdx.x;
    int e = eidx[b];
    float s = g[0] * rsqrtf(v[0] + EPSF);
    float t = bb[0] - m[0] * s;
    const float4* src = (const float4*)(E + (size_t)e * 400);
    float4* dst = (float4*)(xout + (size_t)b * 400);
    for (int i = threadIdx.x; i < 100; i += blockDim.x) {
        float4 u = src[i];
        dst[i] = make_float4(u.x * s + t, u.y * s + t, u.z * s + t, u.w * s + t);
    }
    int r = ridx[b];
    const float* rsrc = R + (size_t)r * 400;
    short* rdst = rout + (size_t)b * 416;
    for (int i = threadIdx.x; i < 416; i += blockDim.x)
        rdst[i] = (i < 400) ? f2bf(rsrc[i]) : (short)0;
}

// fc_w (400 x 37632) f32 -> bf16, same layout
__global__ void cvt_fcw(const float* __restrict__ in, short* __restrict__ out, int n4)
{
    int i = blockIdx.x * blockDim.x + threadIdx.x;
    int stride = gridDim.x * blockDim.x;
    const float4* in4 = (const float4*)in;
    short4* out4 = (short4*)out;
    for (; i < n4; i += stride) {
        float4 v = in4[i];
        out4[i] = make_short4(f2bf(v.x), f2bf(v.y), f2bf(v.z), f2bf(v.w));
    }
}

// fc1_w (864 x 400) f32 -> bf16 padded to ld 416
__global__ void cvt_fc1w_pad(const float* __restrict__ in, short* __restrict__ out)
{
    int i = blockIdx.x * blockDim.x + threadIdx.x;
    if (i >= 864 * 416) return;
    int row = i / 416, col = i - row * 416;
    out[i] = (col < 400) ? f2bf(in[row * 400 + col]) : (short)0;
}

// ---------------------------------------------------------------------------
// per-sample conv (96 out-ch, 9 taps, valid) + BN1 -> bf16 flat[b, o*392+l]
// one block per sample; float4 LDS reads, short8 stores
// ---------------------------------------------------------------------------
__global__ __launch_bounds__(256) void conv_bn1(
    const float* __restrict__ xall, const float* __restrict__ kfall,
    const float* __restrict__ g1, const float* __restrict__ b1,
    const float* __restrict__ m1, const float* __restrict__ v1,
    short* __restrict__ flat, int b_base)
{
    __shared__ float xs[400];
    __shared__ float ks[864];
    __shared__ float s1s[96], t1s[96];
    const int b = b_base + blockIdx.x;
    const int tid = threadIdx.x;
    const float* xr = xall + (size_t)b * 400;
    const float* kr = kfall + (size_t)b * 864;
    for (int i = tid; i < 400; i += 256) xs[i] = xr[i];
    for (int i = tid; i < 864; i += 256) ks[i] = kr[i];
    if (tid < 96) {
        float s = g1[tid] * rsqrtf(v1[tid] + EPSF);
        s1s[tid] = s;
        t1s[tid] = b1[tid] - m1[tid] * s;
    }
    __syncthreads();
    short8* fr8 = (short8*)(flat + (size_t)blockIdx.x * 37632);
    for (int i = tid; i < 4704; i += 256) {     // 4704 = 96*392/8
        int o   = i / 49;                       // 49 short8 vectors per channel
        int ll0 = (i - o * 49) * 8;             // multiple of 8 -> float4 aligned
        const float* kk = &ks[o * 9];
        float xv[16];
        const float4* xp = (const float4*)&xs[ll0];
#pragma unroll
        for (int q = 0; q < 4; ++q) {
            float4 u = xp[q];
            xv[q * 4 + 0] = u.x; xv[q * 4 + 1] = u.y;
            xv[q * 4 + 2] = u.z; xv[q * 4 + 3] = u.w;
        }
        float s1 = s1s[o], t1 = t1s[o];
        short8 outv;
#pragma unroll
        for (int j = 0; j < 8; ++j) {
            float a = 0.f;
#pragma unroll
            for (int f = 0; f < 9; ++f) a += xv[j + f] * kk[f];
            outv[j] = f2bf(a * s1 + t1);
        }
        fr8[i] = outv;
    }
}

// sum NZ split-K partials + fc_b + BN2 + ReLU -> bf16 x_out rows, ld 416 (pad=0)
__global__ void reduce_bn2(const float* __restrict__ hp, int C, int nz,
                           const float* __restrict__ fcb,
                           const float* __restrict__ g2, const float* __restrict__ b2,
                           const float* __restrict__ m2, const float* __restrict__ v2,
                           short* __restrict__ xout, int cb)
{
    int i = blockIdx.x * blockDim.x + threadIdx.x;
    int total = C * 416;
    if (i >= total) return;
    int row = i / 416, col = i - row * 416;
    short val = 0;
    if (col < 400) {
        float s = 0.f;
        size_t stride = (size_t)C * 400;
        size_t basei = (size_t)row * 400 + col;
        for (int k = 0; k < nz; ++k) s += hp[k * stride + basei];
        float sc = g2[col] * rsqrtf(v2[col] + EPSF);
        float hv = (s + fcb[col] - m2[col]) * sc + b2[col];
        val = f2bf(fmaxf(hv, 0.f));
    }
    xout[(size_t)(cb + row) * 416 + col] = val;
}

extern "C" void kernel_launch(void* const* d_in, const int* in_sizes, int n_in,
                              void* d_out, int out_size, void* d_ws, size_t ws_size,
                              hipStream_t stream)
{
    (void)in_sizes; (void)n_in; (void)out_size;
    const int*   e1    = (const int*)d_in[0];
    const int*   r1i   = (const int*)d_in[1];
    const int*   r2i   = (const int*)d_in[2];
    const int*   e2    = (const int*)d_in[3];
    const float* E_w   = (const float*)d_in[4];
    const float* R_w   = (const float*)d_in[5];
    const float* fc1_w = (const float*)d_in[6];
    const float* fc1_b = (const float*)d_in[7];
    const float* fc_w  = (const float*)d_in[8];
    const float* fc_b  = (const float*)d_in[9];
    const float* bn0_g = (const float*)d_in[10];
    const float* bn0_b = (const float*)d_in[11];
    const float* bn0_m = (const float*)d_in[12];
    const float* bn0_v = (const float*)d_in[13];
    const float* bn1_g = (const float*)d_in[14];
    const float* bn1_b = (const float*)d_in[15];
    const float* bn1_m = (const float*)d_in[16];
    const float* bn1_v = (const float*)d_in[17];
    const float* bn2_g = (const float*)d_in[18];
    const float* bn2_b = (const float*)d_in[19];
    const float* bn2_m = (const float*)d_in[20];
    const float* bn2_v = (const float*)d_in[21];
    const float* bbias = (const float*)d_in[22];
    float* out = (float*)d_out;

    char* basep = (char*)d_ws;
    size_t off = 0;
    auto alloc = [&](size_t bytes) -> char* {
        char* p = basep + off;
        off = (off + bytes + 255) & ~(size_t)255;
        return p;
    };
    short* fcw_b  = (short*)alloc(400ULL * 37632 * 2);
    short* fc1w_b = (short*)alloc(864ULL * 416 * 2);
    float* xf     = (float*)alloc(2048ULL * 400 * 4);
    short* rb     = (short*)alloc(2048ULL * 416 * 2);
    float* kf     = (float*)alloc(2048ULL * 864 * 4);
    short* x1b    = (short*)alloc(2048ULL * 416 * 2);
    short* x2b    = (short*)alloc(2048ULL * 416 * 2);
    size_t fixed = off;

    const int NZ = 20;  // split-K ways: grid 16x4x20 = 1280 = exactly 5 blocks/CU
    int CHUNK = 128;
    for (int c = 2048; c >= 128; c >>= 1) {
        size_t need = fixed + ((size_t)c * 400 * NZ * 4 + 256) + ((size_t)c * 37632 * 2 + 256);
        if (need <= ws_size) { CHUNK = c; break; }
    }
    float* hpart = (float*)alloc((size_t)CHUNK * 400 * NZ * 4);
    short* flat  = (short*)alloc((size_t)CHUNK * 37632 * 2);

    // weights -> bf16 (recomputed each call; deterministic)
    cvt_fcw<<<2048, 256, 0, stream>>>(fc_w, fcw_b, 400 * 37632 / 4);
    cvt_fc1w_pad<<<(864 * 416 + 255) / 256, 256, 0, stream>>>(fc1_w, fc1w_b);

    for (int br = 0; br < 2; ++br) {
        const int* eidx = (br == 0) ? e1 : e2;
        const int* ridx = (br == 0) ? r1i : r2i;
        short* xob = (br == 0) ? x1b : x2b;

        gather_fused<<<2048, 128, 0, stream>>>(E_w, eidx, R_w, ridx,
                                               bn0_g, bn0_b, bn0_m, bn0_v, xf, rb);
        // k filters: (2048x400) @ (864x400)^T + fc1_b -> f32 (2048x864)
        gemm_bt<0><<<dim3(16, 7), 256, 0, stream>>>(rb, fc1w_b, kf, 2048, 864, 416, 864, fc1_b);

        for (int cb = 0; cb < 2048; cb += CHUNK) {
            conv_bn1<<<CHUNK, 256, 0, stream>>>(xf, kf, bn1_g, bn1_b, bn1_m, bn1_v, flat, cb);
            // fc: (CHUNK x 37632) @ (400 x 37632)^T, split-K x NZ partials
            gemm_bt<1><<<dim3(CHUNK / 128, 4, NZ), 256, 0, stream>>>(
                flat, fcw_b, hpart, CHUNK, 400, 37632, 400, nullptr);
            reduce_bn2<<<(CHUNK * 416 + 255) / 256, 256, 0, stream>>>(
                hpart, CHUNK, NZ, fc_b, bn2_g, bn2_b, bn2_m, bn2_v, xob, cb);
        }
    }

    // logits = x1 @ x2^T + b_bias[col]  -> f32 (2048x2048)
    gemm_bt<0><<<dim3(16, 16), 256, 0, stream>>>(x1b, x2b, out, 2048, 2048, 416, 2048, bbias);
}

// Round 5
// 365.400 us; speedup vs baseline: 1.1221x; 1.1221x over previous
//
#include <hip/hip_runtime.h>
#include <hip/hip_bf16.h>
#include <stdint.h>

#define EPSF 1e-5f

typedef __attribute__((ext_vector_type(8))) short short8;
typedef __attribute__((ext_vector_type(4))) float f32x4;

__device__ inline short f2bf(float f) {
    union { float f; unsigned u; } x; x.f = f;
    unsigned u = x.u;
    unsigned r = (u + 0x7FFFu + ((u >> 16) & 1u)) >> 16;  // round-to-nearest-even
    return (short)r;
}

__device__ inline f32x4 mfma16x16x32(short8 a, short8 b, f32x4 c) {
    return __builtin_amdgcn_mfma_f32_16x16x32_bf16(a, b, c, 0, 0, 0);
}

// ---------------------------------------------------------------------------
// BT-GEMM: C[M,N] = A[M,KP] * B[N,KP]^T   (A,B bf16-as-short, KP % 32 == 0,
// M % 256 == 0). MODE 0: full-K, += bias[col]. MODE 1: split-K partials.
// Block 256x128, 4 waves (2x2), wave tile 128x64 (8x4 MFMA frags).
//   LDS bytes/FLOP = (128+64)/(128*64) = 1/42.7 -> LDS-BW cap ~36% MfmaUtil
//   (vs 1/32 -> 26% cap of the old 64x64 wave tile, which matched measured).
// 3-deep LDS pipeline (stage t+2 at step t), counted vmcnt(6) mid-loop.
// 16B-block XOR swizzle on BOTH sides (global src + ds_read addr) -> 0 confl.
// ---------------------------------------------------------------------------
template <int MODE>
__global__ __launch_bounds__(256, 2) void gemm_bt(
    const short* __restrict__ A, const short* __restrict__ B,
    float* __restrict__ C, int M, int N, int KP, int ldc,
    const float* __restrict__ bias)
{
    __shared__ alignas(16) short As[3][256 * 32];
    __shared__ alignas(16) short Bs[3][128 * 32];

    const int tid = threadIdx.x;
    const int l   = tid & 63;
    const int w   = tid >> 6;
    const int wr  = w >> 1, wc = w & 1;   // wave tile: rows wr*128, cols wc*64
    const int m0  = blockIdx.x * 256;
    const int n0  = blockIdx.y * 128;

    int k_beg = 0, k_end = KP;
    if (MODE == 1) {
        int steps = KP >> 5;
        long long z = blockIdx.z;
        int s0 = (int)(z * steps / gridDim.z);
        int s1 = (int)((z + 1) * steps / gridDim.z);
        k_beg = s0 << 5;
        k_end = s1 << 5;
    }

    // staging: lane l covers 16B at (row sr, 16B-blk l&3) of a 16-row group;
    // sources LOGICAL blk (l&3)^((sr>>1)&3) from global (LDS write is linear)
    const int sr   = l >> 2;
    const int sc   = ((l & 3) ^ ((sr >> 1) & 3)) * 8;
    // frag read side (same XOR)
    const int lr   = l & 15;
    const int kg   = l >> 4;
    const int kswz = (kg ^ ((lr >> 1) & 3)) * 8;

    // A: 16 groups of 16 rows; wave w stages groups w*4..w*4+3
    const short* gaB[4];
#pragma unroll
    for (int i = 0; i < 4; ++i)
        gaB[i] = A + (size_t)(m0 + (w * 4 + i) * 16 + sr) * KP + sc;
    // B: 8 groups; wave w stages groups w*2..w*2+1 (rows clamped in-bounds)
    const short* gbB[2];
#pragma unroll
    for (int i = 0; i < 2; ++i) {
        int rB = n0 + (w * 2 + i) * 16 + sr;
        if (rB > N - 1) rB = N - 1;
        gbB[i] = B + (size_t)rB * KP + sc;
    }

    auto stage = [&](int buf, int k0) {
#pragma unroll
        for (int i = 0; i < 4; ++i)
            __builtin_amdgcn_global_load_lds(
                (const __attribute__((address_space(1))) void*)(gaB[i] + k0),
                (__attribute__((address_space(3))) void*)(&As[buf][(w * 4 + i) * 512]), 16, 0, 0);
#pragma unroll
        for (int i = 0; i < 2; ++i)
            __builtin_amdgcn_global_load_lds(
                (const __attribute__((address_space(1))) void*)(gbB[i] + k0),
                (__attribute__((address_space(3))) void*)(&Bs[buf][(w * 2 + i) * 512]), 16, 0, 0);
    };

    f32x4 acc[8][4] = {};

    const int nt = (k_end - k_beg) >> 5;
    stage(0, k_beg);
    if (nt > 1) stage(1, k_beg + 32);

    int rd = 0;
    for (int t = 0; t < nt; ++t) {
        if (t + 1 < nt) { asm volatile("s_waitcnt vmcnt(6)" ::: "memory"); }
        else            { asm volatile("s_waitcnt vmcnt(0)" ::: "memory"); }
        __builtin_amdgcn_s_barrier();
        __builtin_amdgcn_sched_barrier(0);

        if (t + 2 < nt) {
            int wb = rd + 2; if (wb >= 3) wb -= 3;
            stage(wb, k_beg + ((t + 2) << 5));
        }

        short8 af[8], bfr[4];
#pragma unroll
        for (int mi = 0; mi < 8; ++mi)
            af[mi] = *(const short8*)&As[rd][(wr * 128 + mi * 16 + lr) * 32 + kswz];
#pragma unroll
        for (int ni = 0; ni < 4; ++ni)
            bfr[ni] = *(const short8*)&Bs[rd][(wc * 64 + ni * 16 + lr) * 32 + kswz];
#pragma unroll
        for (int mi = 0; mi < 8; ++mi)
#pragma unroll
            for (int ni = 0; ni < 4; ++ni)
                acc[mi][ni] = mfma16x16x32(af[mi], bfr[ni], acc[mi][ni]);

        asm volatile("s_waitcnt lgkmcnt(0)" ::: "memory");
        if (++rd == 3) rd = 0;
    }

    float* Cb = C;
    if (MODE == 1) Cb = C + (size_t)blockIdx.z * M * ldc;

#pragma unroll
    for (int ni = 0; ni < 4; ++ni) {
        int col = n0 + wc * 64 + ni * 16 + lr;
        if (col >= N) continue;
        float bv = (MODE == 0 && bias) ? bias[col] : 0.0f;
#pragma unroll
        for (int mi = 0; mi < 8; ++mi) {
            int row0 = m0 + wr * 128 + mi * 16 + kg * 4;
#pragma unroll
            for (int r = 0; r < 4; ++r)
                Cb[(size_t)(row0 + r) * ldc + col] = acc[mi][ni][r] + bv;
        }
    }
}

// ---------------------------------------------------------------------------
// fused gathers: entity row + BN0 -> f32 x[2048,400]; relation row -> bf16
// padded to 416 cols
// ---------------------------------------------------------------------------
__global__ void gather_fused(const float* __restrict__ E, const int* __restrict__ eidx,
                             const float* __restrict__ R, const int* __restrict__ ridx,
                             const float* g, const float* bb, const float* m,
                             const float* v, float* __restrict__ xout,
                             short* __restrict__ rout)
{
    int b = blockIdx.x;
    int e = eidx[b];
    float s = g[0] * rsqrtf(v[0] + EPSF);
    float t = bb[0] - m[0] * s;
    const float4* src = (const float4*)(E + (size_t)e * 400);
    float4* dst = (float4*)(xout + (size_t)b * 400);
    for (int i = threadIdx.x; i < 100; i += blockDim.x) {
        float4 u = src[i];
        dst[i] = make_float4(u.x * s + t, u.y * s + t, u.z * s + t, u.w * s + t);
    }
    int r = ridx[b];
    const float* rsrc = R + (size_t)r * 400;
    short* rdst = rout + (size_t)b * 416;
    for (int i = threadIdx.x; i < 416; i += blockDim.x)
        rdst[i] = (i < 400) ? f2bf(rsrc[i]) : (short)0;
}

// fc_w (400 x 37632) f32 -> bf16, same layout
__global__ void cvt_fcw(const float* __restrict__ in, short* __restrict__ out, int n4)
{
    int i = blockIdx.x * blockDim.x + threadIdx.x;
    int stride = gridDim.x * blockDim.x;
    const float4* in4 = (const float4*)in;
    short4* out4 = (short4*)out;
    for (; i < n4; i += stride) {
        float4 v = in4[i];
        out4[i] = make_short4(f2bf(v.x), f2bf(v.y), f2bf(v.z), f2bf(v.w));
    }
}

// fc1_w (864 x 400) f32 -> bf16 padded to ld 416
__global__ void cvt_fc1w_pad(const float* __restrict__ in, short* __restrict__ out)
{
    int i = blockIdx.x * blockDim.x + threadIdx.x;
    if (i >= 864 * 416) return;
    int row = i / 416, col = i - row * 416;
    out[i] = (col < 400) ? f2bf(in[row * 400 + col]) : (short)0;
}

// ---------------------------------------------------------------------------
// per-sample conv (96 out-ch, 9 taps, valid) + BN1 -> bf16 flat[b, o*392+l]
// one block per sample; float4 LDS reads, short8 stores
// ---------------------------------------------------------------------------
__global__ __launch_bounds__(256) void conv_bn1(
    const float* __restrict__ xall, const float* __restrict__ kfall,
    const float* __restrict__ g1, const float* __restrict__ b1,
    const float* __restrict__ m1, const float* __restrict__ v1,
    short* __restrict__ flat, int b_base)
{
    __shared__ float xs[400];
    __shared__ float ks[864];
    __shared__ float s1s[96], t1s[96];
    const int b = b_base + blockIdx.x;
    const int tid = threadIdx.x;
    const float* xr = xall + (size_t)b * 400;
    const float* kr = kfall + (size_t)b * 864;
    for (int i = tid; i < 400; i += 256) xs[i] = xr[i];
    for (int i = tid; i < 864; i += 256) ks[i] = kr[i];
    if (tid < 96) {
        float s = g1[tid] * rsqrtf(v1[tid] + EPSF);
        s1s[tid] = s;
        t1s[tid] = b1[tid] - m1[tid] * s;
    }
    __syncthreads();
    short8* fr8 = (short8*)(flat + (size_t)blockIdx.x * 37632);
    for (int i = tid; i < 4704; i += 256) {     // 4704 = 96*392/8
        int o   = i / 49;                       // 49 short8 vectors per channel
        int ll0 = (i - o * 49) * 8;             // multiple of 8 -> float4 aligned
        const float* kk = &ks[o * 9];
        float xv[16];
        const float4* xp = (const float4*)&xs[ll0];
#pragma unroll
        for (int q = 0; q < 4; ++q) {
            float4 u = xp[q];
            xv[q * 4 + 0] = u.x; xv[q * 4 + 1] = u.y;
            xv[q * 4 + 2] = u.z; xv[q * 4 + 3] = u.w;
        }
        float s1 = s1s[o], t1 = t1s[o];
        short8 outv;
#pragma unroll
        for (int j = 0; j < 8; ++j) {
            float a = 0.f;
#pragma unroll
            for (int f = 0; f < 9; ++f) a += xv[j + f] * kk[f];
            outv[j] = f2bf(a * s1 + t1);
        }
        fr8[i] = outv;
    }
}

// sum NZ split-K partials + fc_b + BN2 + ReLU -> bf16 x_out rows, ld 416 (pad=0)
__global__ void reduce_bn2(const float* __restrict__ hp, int C, int nz,
                           const float* __restrict__ fcb,
                           const float* __restrict__ g2, const float* __restrict__ b2,
                           const float* __restrict__ m2, const float* __restrict__ v2,
                           short* __restrict__ xout, int cb)
{
    int i = blockIdx.x * blockDim.x + threadIdx.x;
    int total = C * 416;
    if (i >= total) return;
    int row = i / 416, col = i - row * 416;
    short val = 0;
    if (col < 400) {
        float s = 0.f;
        size_t stride = (size_t)C * 400;
        size_t basei = (size_t)row * 400 + col;
        for (int k = 0; k < nz; ++k) s += hp[k * stride + basei];
        float sc = g2[col] * rsqrtf(v2[col] + EPSF);
        float hv = (s + fcb[col] - m2[col]) * sc + b2[col];
        val = f2bf(fmaxf(hv, 0.f));
    }
    xout[(size_t)(cb + row) * 416 + col] = val;
}

extern "C" void kernel_launch(void* const* d_in, const int* in_sizes, int n_in,
                              void* d_out, int out_size, void* d_ws, size_t ws_size,
                              hipStream_t stream)
{
    (void)in_sizes; (void)n_in; (void)out_size;
    const int*   e1    = (const int*)d_in[0];
    const int*   r1i   = (const int*)d_in[1];
    const int*   r2i   = (const int*)d_in[2];
    const int*   e2    = (const int*)d_in[3];
    const float* E_w   = (const float*)d_in[4];
    const float* R_w   = (const float*)d_in[5];
    const float* fc1_w = (const float*)d_in[6];
    const float* fc1_b = (const float*)d_in[7];
    const float* fc_w  = (const float*)d_in[8];
    const float* fc_b  = (const float*)d_in[9];
    const float* bn0_g = (const float*)d_in[10];
    const float* bn0_b = (const float*)d_in[11];
    const float* bn0_m = (const float*)d_in[12];
    const float* bn0_v = (const float*)d_in[13];
    const float* bn1_g = (const float*)d_in[14];
    const float* bn1_b = (const float*)d_in[15];
    const float* bn1_m = (const float*)d_in[16];
    const float* bn1_v = (const float*)d_in[17];
    const float* bn2_g = (const float*)d_in[18];
    const float* bn2_b = (const float*)d_in[19];
    const float* bn2_m = (const float*)d_in[20];
    const float* bn2_v = (const float*)d_in[21];
    const float* bbias = (const float*)d_in[22];
    float* out = (float*)d_out;

    char* basep = (char*)d_ws;
    size_t off = 0;
    auto alloc = [&](size_t bytes) -> char* {
        char* p = basep + off;
        off = (off + bytes + 255) & ~(size_t)255;
        return p;
    };
    short* fcw_b  = (short*)alloc(400ULL * 37632 * 2);
    short* fc1w_b = (short*)alloc(864ULL * 416 * 2);
    float* xf     = (float*)alloc(2048ULL * 400 * 4);
    short* rb     = (short*)alloc(2048ULL * 416 * 2);
    float* kf     = (float*)alloc(2048ULL * 864 * 4);
    short* x1b    = (short*)alloc(2048ULL * 416 * 2);
    short* x2b    = (short*)alloc(2048ULL * 416 * 2);
    size_t fixed = off;

    const int NZ = 16;  // split-K ways: grid 8x4x16 = 512 = 2 blocks/CU
    int CHUNK = 256;
    for (int c = 2048; c >= 256; c >>= 1) {
        size_t need = fixed + ((size_t)c * 400 * NZ * 4 + 256) + ((size_t)c * 37632 * 2 + 256);
        if (need <= ws_size) { CHUNK = c; break; }
    }
    float* hpart = (float*)alloc((size_t)CHUNK * 400 * NZ * 4);
    short* flat  = (short*)alloc((size_t)CHUNK * 37632 * 2);

    // weights -> bf16 (recomputed each call; deterministic)
    cvt_fcw<<<2048, 256, 0, stream>>>(fc_w, fcw_b, 400 * 37632 / 4);
    cvt_fc1w_pad<<<(864 * 416 + 255) / 256, 256, 0, stream>>>(fc1_w, fc1w_b);

    for (int br = 0; br < 2; ++br) {
        const int* eidx = (br == 0) ? e1 : e2;
        const int* ridx = (br == 0) ? r1i : r2i;
        short* xob = (br == 0) ? x1b : x2b;

        gather_fused<<<2048, 128, 0, stream>>>(E_w, eidx, R_w, ridx,
                                               bn0_g, bn0_b, bn0_m, bn0_v, xf, rb);
        // k filters: (2048x400) @ (864x400)^T + fc1_b -> f32 (2048x864)
        gemm_bt<0><<<dim3(8, 7), 256, 0, stream>>>(rb, fc1w_b, kf, 2048, 864, 416, 864, fc1_b);

        for (int cb = 0; cb < 2048; cb += CHUNK) {
            conv_bn1<<<CHUNK, 256, 0, stream>>>(xf, kf, bn1_g, bn1_b, bn1_m, bn1_v, flat, cb);
            // fc: (CHUNK x 37632) @ (400 x 37632)^T, split-K x NZ partials
            gemm_bt<1><<<dim3(CHUNK / 256, 4, NZ), 256, 0, stream>>>(
                flat, fcw_b, hpart, CHUNK, 400, 37632, 400, nullptr);
            reduce_bn2<<<(CHUNK * 416 + 255) / 256, 256, 0, stream>>>(
                hpart, CHUNK, NZ, fc_b, bn2_g, bn2_b, bn2_m, bn2_v, xob, cb);
        }
    }

    // logits = x1 @ x2^T + b_bias[col]  -> f32 (2048x2048)
    gemm_bt<0><<<dim3(8, 16), 256, 0, stream>>>(x1b, x2b, out, 2048, 2048, 416, 2048, bbias);
}

// Round 6
// 352.388 us; speedup vs baseline: 1.1635x; 1.0369x over previous
//
#include <hip/hip_runtime.h>
#include <hip/hip_bf16.h>
#include <stdint.h>

#define EPSF 1e-5f

typedef __attribute__((ext_vector_type(8))) short short8;
typedef __attribute__((ext_vector_type(4))) float f32x4;

__device__ inline short f2bf(float f) {
    union { float f; unsigned u; } x; x.f = f;
    unsigned u = x.u;
    unsigned r = (u + 0x7FFFu + ((u >> 16) & 1u)) >> 16;  // round-to-nearest-even
    return (short)r;
}

__device__ inline f32x4 mfma16x16x32(short8 a, short8 b, f32x4 c) {
    return __builtin_amdgcn_mfma_f32_16x16x32_bf16(a, b, c, 0, 0, 0);
}

// ---------------------------------------------------------------------------
// 8-phase 256x256 split-K BT-GEMM (m201-style): C_partial[z] = A*B^T slice.
// A[M,KP], B[N,KP] bf16, KP%64==0, M%256==0. 8 waves (2x4), wave tile 128x64.
// LDS: per operand 2 dbuf x 2 k-half slabs of [256 rows][32 cols] = 128 KB.
// Per K-tile (BK=64) 4 phases: {ds_read subtile; stage 1 half; bar;
// setprio(1) 16 MFMA setprio(0); sched_barrier; bar}. Stage schedule
// (slot-safe: overwrite issues >=1 phase after last read of slab completes):
//   P1: t+1 A k1 | P2: t+1 B k1 | P3: t+2 A k0 | P4: t+2 B k0
// Boundary wait vmcnt(4) (=2 halves in flight) guarantees tile t+1 resident;
// vmcnt(0) fallback when tail stages were skipped.
// ---------------------------------------------------------------------------
__global__ __launch_bounds__(512, 1) void gemm_fc8(
    const short* __restrict__ A, const short* __restrict__ B,
    float* __restrict__ C, int M, int N, int KP, int ldc)
{
    __shared__ alignas(16) short As[2][2][256 * 32];
    __shared__ alignas(16) short Bs[2][2][256 * 32];

    const int tid = threadIdx.x;
    const int l   = tid & 63;
    const int w   = tid >> 6;        // 0..7
    const int wr  = w >> 2;          // 0..1  (row half)
    const int wc  = w & 3;           // 0..3  (col quarter)
    const int m0  = blockIdx.x * 256;
    const int n0  = blockIdx.y * 256;

    const int tiles = KP >> 6;
    long long z = blockIdx.z;
    const int t0 = (int)(z * tiles / gridDim.z);
    const int t1 = (int)((z + 1) * tiles / gridDim.z);
    const int nt = t1 - t0;
    const int k_beg = t0 << 6;

    const int sr   = l >> 2;
    const int sc   = ((l & 3) ^ ((sr >> 1) & 3)) * 8;
    const int lr   = l & 15;
    const int kg   = l >> 4;
    const int kswz = (kg ^ ((lr >> 1) & 3)) * 8;

    // wave w stages 16-row groups {w, w+8} of each 256x32 slab
    const short* gA[2]; const short* gB[2];
#pragma unroll
    for (int i = 0; i < 2; ++i) {
        int g = w + i * 8;
        gA[i] = A + (size_t)(m0 + g * 16 + sr) * KP + sc;
        int rB = n0 + g * 16 + sr; if (rB > N - 1) rB = N - 1;
        gB[i] = B + (size_t)rB * KP + sc;
    }

    auto stage_half = [&](int hs) {
        int ths = hs >> 2;
        if (ths >= nt) return;
        int wh  = hs & 3;
        int isB = wh & 1, kh = wh >> 1;
        int kof = k_beg + (ths << 6) + (kh << 5);
        int d   = ths & 1;
        short* slab = isB ? &Bs[d][kh][0] : &As[d][kh][0];
        const short* const* gp = isB ? gB : gA;
#pragma unroll
        for (int i = 0; i < 2; ++i) {
            int g = w + i * 8;
            __builtin_amdgcn_global_load_lds(
                (const __attribute__((address_space(1))) void*)(gp[i] + kof),
                (__attribute__((address_space(3))) void*)(slab + g * 512), 16, 0, 0);
        }
    };

    f32x4 acc[8][4] = {};

    // prologue: tile0 all 4 halves + tile1 k0 halves (order: Ak0,Bk0,Ak1,Bk1,Ak0',Bk0')
    for (int hs = 0; hs < 6; ++hs) stage_half(hs);
    if (nt > 1) { asm volatile("s_waitcnt vmcnt(4)" ::: "memory"); }
    else        { asm volatile("s_waitcnt vmcnt(0)" ::: "memory"); }
    __builtin_amdgcn_s_barrier();

    int hs = 6;
    for (int j = 0; j < nt; ++j) {
        const int d = j & 1;
        const short* A0 = &As[d][0][0];
        const short* A1 = &As[d][1][0];
        const short* B0 = &Bs[d][0][0];
        const short* B1 = &Bs[d][1][0];
        short8 af[4], bf[4];

        // ---- P1: k-half 0, mi 0..3 (loads B k0)
#pragma unroll
        for (int q = 0; q < 4; ++q)
            af[q] = *(const short8*)&A0[(wr * 128 + q * 16 + lr) * 32 + kswz];
#pragma unroll
        for (int n = 0; n < 4; ++n)
            bf[n] = *(const short8*)&B0[(wc * 64 + n * 16 + lr) * 32 + kswz];
        stage_half(hs++);
        __builtin_amdgcn_s_barrier();
        __builtin_amdgcn_s_setprio(1);
#pragma unroll
        for (int q = 0; q < 4; ++q)
#pragma unroll
            for (int n = 0; n < 4; ++n)
                acc[q][n] = mfma16x16x32(af[q], bf[n], acc[q][n]);
        __builtin_amdgcn_s_setprio(0);
        __builtin_amdgcn_sched_barrier(0);
        __builtin_amdgcn_s_barrier();

        // ---- P2: k-half 0, mi 4..7 (bf reused)
#pragma unroll
        for (int q = 0; q < 4; ++q)
            af[q] = *(const short8*)&A0[(wr * 128 + (q + 4) * 16 + lr) * 32 + kswz];
        stage_half(hs++);
        __builtin_amdgcn_s_barrier();
        __builtin_amdgcn_s_setprio(1);
#pragma unroll
        for (int q = 0; q < 4; ++q)
#pragma unroll
            for (int n = 0; n < 4; ++n)
                acc[q + 4][n] = mfma16x16x32(af[q], bf[n], acc[q + 4][n]);
        __builtin_amdgcn_s_setprio(0);
        __builtin_amdgcn_sched_barrier(0);
        __builtin_amdgcn_s_barrier();

        // ---- P3: k-half 1, mi 0..3 (loads B k1)
#pragma unroll
        for (int q = 0; q < 4; ++q)
            af[q] = *(const short8*)&A1[(wr * 128 + q * 16 + lr) * 32 + kswz];
#pragma unroll
        for (int n = 0; n < 4; ++n)
            bf[n] = *(const short8*)&B1[(wc * 64 + n * 16 + lr) * 32 + kswz];
        stage_half(hs++);
        __builtin_amdgcn_s_barrier();
        __builtin_amdgcn_s_setprio(1);
#pragma unroll
        for (int q = 0; q < 4; ++q)
#pragma unroll
            for (int n = 0; n < 4; ++n)
                acc[q][n] = mfma16x16x32(af[q], bf[n], acc[q][n]);
        __builtin_amdgcn_s_setprio(0);
        __builtin_amdgcn_sched_barrier(0);
        __builtin_amdgcn_s_barrier();

        // ---- P4: k-half 1, mi 4..7; boundary vmcnt before closing barrier
#pragma unroll
        for (int q = 0; q < 4; ++q)
            af[q] = *(const short8*)&A1[(wr * 128 + (q + 4) * 16 + lr) * 32 + kswz];
        stage_half(hs++);
        __builtin_amdgcn_s_barrier();
        __builtin_amdgcn_s_setprio(1);
#pragma unroll
        for (int q = 0; q < 4; ++q)
#pragma unroll
            for (int n = 0; n < 4; ++n)
                acc[q + 4][n] = mfma16x16x32(af[q], bf[n], acc[q + 4][n]);
        __builtin_amdgcn_s_setprio(0);
        __builtin_amdgcn_sched_barrier(0);
        if (j + 2 < nt) { asm volatile("s_waitcnt vmcnt(4)" ::: "memory"); }
        else            { asm volatile("s_waitcnt vmcnt(0)" ::: "memory"); }
        __builtin_amdgcn_s_barrier();
    }

    float* Cb = C + (size_t)blockIdx.z * M * ldc;
#pragma unroll
    for (int ni = 0; ni < 4; ++ni) {
        int col = n0 + wc * 64 + ni * 16 + lr;
        if (col >= N) continue;
#pragma unroll
        for (int mi = 0; mi < 8; ++mi) {
            int row0 = m0 + wr * 128 + mi * 16 + kg * 4;
#pragma unroll
            for (int r = 0; r < 4; ++r)
                Cb[(size_t)(row0 + r) * ldc + col] = acc[mi][ni][r];
        }
    }
}

// ---------------------------------------------------------------------------
// BT-GEMM (round-5 proven): block 256x128, 4 waves, wave tile 128x64,
// 3-deep pipeline, counted vmcnt(6). Used for fc1 + logits (MODE 0).
// ---------------------------------------------------------------------------
template <int MODE>
__global__ __launch_bounds__(256, 2) void gemm_bt(
    const short* __restrict__ A, const short* __restrict__ B,
    float* __restrict__ C, int M, int N, int KP, int ldc,
    const float* __restrict__ bias)
{
    __shared__ alignas(16) short As[3][256 * 32];
    __shared__ alignas(16) short Bs[3][128 * 32];

    const int tid = threadIdx.x;
    const int l   = tid & 63;
    const int w   = tid >> 6;
    const int wr  = w >> 1, wc = w & 1;
    const int m0  = blockIdx.x * 256;
    const int n0  = blockIdx.y * 128;

    int k_beg = 0, k_end = KP;
    if (MODE == 1) {
        int steps = KP >> 5;
        long long z = blockIdx.z;
        int s0 = (int)(z * steps / gridDim.z);
        int s1 = (int)((z + 1) * steps / gridDim.z);
        k_beg = s0 << 5;
        k_end = s1 << 5;
    }

    const int sr   = l >> 2;
    const int sc   = ((l & 3) ^ ((sr >> 1) & 3)) * 8;
    const int lr   = l & 15;
    const int kg   = l >> 4;
    const int kswz = (kg ^ ((lr >> 1) & 3)) * 8;

    const short* gaB[4];
#pragma unroll
    for (int i = 0; i < 4; ++i)
        gaB[i] = A + (size_t)(m0 + (w * 4 + i) * 16 + sr) * KP + sc;
    const short* gbB[2];
#pragma unroll
    for (int i = 0; i < 2; ++i) {
        int rB = n0 + (w * 2 + i) * 16 + sr;
        if (rB > N - 1) rB = N - 1;
        gbB[i] = B + (size_t)rB * KP + sc;
    }

    auto stage = [&](int buf, int k0) {
#pragma unroll
        for (int i = 0; i < 4; ++i)
            __builtin_amdgcn_global_load_lds(
                (const __attribute__((address_space(1))) void*)(gaB[i] + k0),
                (__attribute__((address_space(3))) void*)(&As[buf][(w * 4 + i) * 512]), 16, 0, 0);
#pragma unroll
        for (int i = 0; i < 2; ++i)
            __builtin_amdgcn_global_load_lds(
                (const __attribute__((address_space(1))) void*)(gbB[i] + k0),
                (__attribute__((address_space(3))) void*)(&Bs[buf][(w * 2 + i) * 512]), 16, 0, 0);
    };

    f32x4 acc[8][4] = {};

    const int nt = (k_end - k_beg) >> 5;
    stage(0, k_beg);
    if (nt > 1) stage(1, k_beg + 32);

    int rd = 0;
    for (int t = 0; t < nt; ++t) {
        if (t + 1 < nt) { asm volatile("s_waitcnt vmcnt(6)" ::: "memory"); }
        else            { asm volatile("s_waitcnt vmcnt(0)" ::: "memory"); }
        __builtin_amdgcn_s_barrier();
        __builtin_amdgcn_sched_barrier(0);

        if (t + 2 < nt) {
            int wb = rd + 2; if (wb >= 3) wb -= 3;
            stage(wb, k_beg + ((t + 2) << 5));
        }

        short8 af[8], bfr[4];
#pragma unroll
        for (int mi = 0; mi < 8; ++mi)
            af[mi] = *(const short8*)&As[rd][(wr * 128 + mi * 16 + lr) * 32 + kswz];
#pragma unroll
        for (int ni = 0; ni < 4; ++ni)
            bfr[ni] = *(const short8*)&Bs[rd][(wc * 64 + ni * 16 + lr) * 32 + kswz];
#pragma unroll
        for (int mi = 0; mi < 8; ++mi)
#pragma unroll
            for (int ni = 0; ni < 4; ++ni)
                acc[mi][ni] = mfma16x16x32(af[mi], bfr[ni], acc[mi][ni]);

        asm volatile("s_waitcnt lgkmcnt(0)" ::: "memory");
        if (++rd == 3) rd = 0;
    }

    float* Cb = C;
    if (MODE == 1) Cb = C + (size_t)blockIdx.z * M * ldc;

#pragma unroll
    for (int ni = 0; ni < 4; ++ni) {
        int col = n0 + wc * 64 + ni * 16 + lr;
        if (col >= N) continue;
        float bv = (MODE == 0 && bias) ? bias[col] : 0.0f;
#pragma unroll
        for (int mi = 0; mi < 8; ++mi) {
            int row0 = m0 + wr * 128 + mi * 16 + kg * 4;
#pragma unroll
            for (int r = 0; r < 4; ++r)
                Cb[(size_t)(row0 + r) * ldc + col] = acc[mi][ni][r] + bv;
        }
    }
}

// ---------------------------------------------------------------------------
// fused gathers: entity row + BN0 -> f32 x[2048,400]; relation row -> bf16
// padded to 416 cols
// ---------------------------------------------------------------------------
__global__ void gather_fused(const float* __restrict__ E, const int* __restrict__ eidx,
                             const float* __restrict__ R, const int* __restrict__ ridx,
                             const float* g, const float* bb, const float* m,
                             const float* v, float* __restrict__ xout,
                             short* __restrict__ rout)
{
    int b = blockIdx.x;
    int e = eidx[b];
    float s = g[0] * rsqrtf(v[0] + EPSF);
    float t = bb[0] - m[0] * s;
    const float4* src = (const float4*)(E + (size_t)e * 400);
    float4* dst = (float4*)(xout + (size_t)b * 400);
    for (int i = threadIdx.x; i < 100; i += blockDim.x) {
        float4 u = src[i];
        dst[i] = make_float4(u.x * s + t, u.y * s + t, u.z * s + t, u.w * s + t);
    }
    int r = ridx[b];
    const float* rsrc = R + (size_t)r * 400;
    short* rdst = rout + (size_t)b * 416;
    for (int i = threadIdx.x; i < 416; i += blockDim.x)
        rdst[i] = (i < 400) ? f2bf(rsrc[i]) : (short)0;
}

// fc_w (400 x 37632) f32 -> bf16, same layout
__global__ void cvt_fcw(const float* __restrict__ in, short* __restrict__ out, int n4)
{
    int i = blockIdx.x * blockDim.x + threadIdx.x;
    int stride = gridDim.x * blockDim.x;
    const float4* in4 = (const float4*)in;
    short4* out4 = (short4*)out;
    for (; i < n4; i += stride) {
        float4 v = in4[i];
        out4[i] = make_short4(f2bf(v.x), f2bf(v.y), f2bf(v.z), f2bf(v.w));
    }
}

// fc1_w (864 x 400) f32 -> bf16 padded to ld 416
__global__ void cvt_fc1w_pad(const float* __restrict__ in, short* __restrict__ out)
{
    int i = blockIdx.x * blockDim.x + threadIdx.x;
    if (i >= 864 * 416) return;
    int row = i / 416, col = i - row * 416;
    out[i] = (col < 400) ? f2bf(in[row * 400 + col]) : (short)0;
}

// ---------------------------------------------------------------------------
// per-sample conv (96 out-ch, 9 taps, valid) + BN1 -> bf16 flat[b, o*392+l]
// ---------------------------------------------------------------------------
__global__ __launch_bounds__(256) void conv_bn1(
    const float* __restrict__ xall, const float* __restrict__ kfall,
    const float* __restrict__ g1, const float* __restrict__ b1,
    const float* __restrict__ m1, const float* __restrict__ v1,
    short* __restrict__ flat, int b_base)
{
    __shared__ float xs[400];
    __shared__ float ks[864];
    __shared__ float s1s[96], t1s[96];
    const int b = b_base + blockIdx.x;
    const int tid = threadIdx.x;
    const float* xr = xall + (size_t)b * 400;
    const float* kr = kfall + (size_t)b * 864;
    for (int i = tid; i < 400; i += 256) xs[i] = xr[i];
    for (int i = tid; i < 864; i += 256) ks[i] = kr[i];
    if (tid < 96) {
        float s = g1[tid] * rsqrtf(v1[tid] + EPSF);
        s1s[tid] = s;
        t1s[tid] = b1[tid] - m1[tid] * s;
    }
    __syncthreads();
    short8* fr8 = (short8*)(flat + (size_t)blockIdx.x * 37632);
    for (int i = tid; i < 4704; i += 256) {
        int o   = i / 49;
        int ll0 = (i - o * 49) * 8;
        const float* kk = &ks[o * 9];
        float xv[16];
        const float4* xp = (const float4*)&xs[ll0];
#pragma unroll
        for (int q = 0; q < 4; ++q) {
            float4 u = xp[q];
            xv[q * 4 + 0] = u.x; xv[q * 4 + 1] = u.y;
            xv[q * 4 + 2] = u.z; xv[q * 4 + 3] = u.w;
        }
        float s1 = s1s[o], t1 = t1s[o];
        short8 outv;
#pragma unroll
        for (int j = 0; j < 8; ++j) {
            float a = 0.f;
#pragma unroll
            for (int f = 0; f < 9; ++f) a += xv[j + f] * kk[f];
            outv[j] = f2bf(a * s1 + t1);
        }
        fr8[i] = outv;
    }
}

// sum NZ split-K partials + fc_b + BN2 + ReLU -> bf16 x_out rows, ld 416 (pad=0)
__global__ void reduce_bn2(const float* __restrict__ hp, int C, int nz,
                           const float* __restrict__ fcb,
                           const float* __restrict__ g2, const float* __restrict__ b2,
                           const float* __restrict__ m2, const float* __restrict__ v2,
                           short* __restrict__ xout, int cb)
{
    int i = blockIdx.x * blockDim.x + threadIdx.x;
    int total = C * 416;
    if (i >= total) return;
    int row = i / 416, col = i - row * 416;
    short val = 0;
    if (col < 400) {
        float s = 0.f;
        size_t stride = (size_t)C * 400;
        size_t basei = (size_t)row * 400 + col;
        for (int k = 0; k < nz; ++k) s += hp[k * stride + basei];
        float sc = g2[col] * rsqrtf(v2[col] + EPSF);
        float hv = (s + fcb[col] - m2[col]) * sc + b2[col];
        val = f2bf(fmaxf(hv, 0.f));
    }
    xout[(size_t)(cb + row) * 416 + col] = val;
}

extern "C" void kernel_launch(void* const* d_in, const int* in_sizes, int n_in,
                              void* d_out, int out_size, void* d_ws, size_t ws_size,
                              hipStream_t stream)
{
    (void)in_sizes; (void)n_in; (void)out_size;
    const int*   e1    = (const int*)d_in[0];
    const int*   r1i   = (const int*)d_in[1];
    const int*   r2i   = (const int*)d_in[2];
    const int*   e2    = (const int*)d_in[3];
    const float* E_w   = (const float*)d_in[4];
    const float* R_w   = (const float*)d_in[5];
    const float* fc1_w = (const float*)d_in[6];
    const float* fc1_b = (const float*)d_in[7];
    const float* fc_w  = (const float*)d_in[8];
    const float* fc_b  = (const float*)d_in[9];
    const float* bn0_g = (const float*)d_in[10];
    const float* bn0_b = (const float*)d_in[11];
    const float* bn0_m = (const float*)d_in[12];
    const float* bn0_v = (const float*)d_in[13];
    const float* bn1_g = (const float*)d_in[14];
    const float* bn1_b = (const float*)d_in[15];
    const float* bn1_m = (const float*)d_in[16];
    const float* bn1_v = (const float*)d_in[17];
    const float* bn2_g = (const float*)d_in[18];
    const float* bn2_b = (const float*)d_in[19];
    const float* bn2_m = (const float*)d_in[20];
    const float* bn2_v = (const float*)d_in[21];
    const float* bbias = (const float*)d_in[22];
    float* out = (float*)d_out;

    char* basep = (char*)d_ws;
    size_t off = 0;
    auto alloc = [&](size_t bytes) -> char* {
        char* p = basep + off;
        off = (off + bytes + 255) & ~(size_t)255;
        return p;
    };
    short* fcw_b  = (short*)alloc(400ULL * 37632 * 2);
    short* fc1w_b = (short*)alloc(864ULL * 416 * 2);
    float* xf     = (float*)alloc(2048ULL * 400 * 4);
    short* rb     = (short*)alloc(2048ULL * 416 * 2);
    float* kf     = (float*)alloc(2048ULL * 864 * 4);
    short* x1b    = (short*)alloc(2048ULL * 416 * 2);
    short* x2b    = (short*)alloc(2048ULL * 416 * 2);
    size_t fixed = off;

    const int NZ = 16;  // split-K ways for the fc GEMM (grid 8x2x16 = 256 blocks)
    int CHUNK = 256;
    for (int c = 2048; c >= 256; c >>= 1) {
        size_t need = fixed + ((size_t)c * 400 * NZ * 4 + 256) + ((size_t)c * 37632 * 2 + 256);
        if (need <= ws_size) { CHUNK = c; break; }
    }
    float* hpart = (float*)alloc((size_t)CHUNK * 400 * NZ * 4);
    short* flat  = (short*)alloc((size_t)CHUNK * 37632 * 2);

    // weights -> bf16 (recomputed each call; deterministic)
    cvt_fcw<<<2048, 256, 0, stream>>>(fc_w, fcw_b, 400 * 37632 / 4);
    cvt_fc1w_pad<<<(864 * 416 + 255) / 256, 256, 0, stream>>>(fc1_w, fc1w_b);

    for (int br = 0; br < 2; ++br) {
        const int* eidx = (br == 0) ? e1 : e2;
        const int* ridx = (br == 0) ? r1i : r2i;
        short* xob = (br == 0) ? x1b : x2b;

        gather_fused<<<2048, 128, 0, stream>>>(E_w, eidx, R_w, ridx,
                                               bn0_g, bn0_b, bn0_m, bn0_v, xf, rb);
        // k filters: (2048x400) @ (864x400)^T + fc1_b -> f32 (2048x864)
        gemm_bt<0><<<dim3(8, 7), 256, 0, stream>>>(rb, fc1w_b, kf, 2048, 864, 416, 864, fc1_b);

        for (int cb = 0; cb < 2048; cb += CHUNK) {
            conv_bn1<<<CHUNK, 256, 0, stream>>>(xf, kf, bn1_g, bn1_b, bn1_m, bn1_v, flat, cb);
            // fc: (CHUNK x 37632) @ (400 x 37632)^T, 8-phase 256^2, split-K x NZ
            gemm_fc8<<<dim3(CHUNK / 256, 2, NZ), 512, 0, stream>>>(
                flat, fcw_b, hpart, CHUNK, 400, 37632, 400);
            reduce_bn2<<<(CHUNK * 416 + 255) / 256, 256, 0, stream>>>(
                hpart, CHUNK, NZ, fc_b, bn2_g, bn2_b, bn2_m, bn2_v, xob, cb);
        }
    }

    // logits = x1 @ x2^T + b_bias[col]  -> f32 (2048x2048)
    gemm_bt<0><<<dim3(8, 16), 256, 0, stream>>>(x1b, x2b, out, 2048, 2048, 416, 2048, bbias);
}

// Round 7
// 346.222 us; speedup vs baseline: 1.1842x; 1.0178x over previous
//
#include <hip/hip_runtime.h>
#include <hip/hip_bf16.h>
#include <stdint.h>

#define EPSF 1e-5f

typedef __attribute__((ext_vector_type(8))) short short8;
typedef __attribute__((ext_vector_type(4))) float f32x4;

__device__ inline short f2bf(float f) {
    union { float f; unsigned u; } x; x.f = f;
    unsigned u = x.u;
    unsigned r = (u + 0x7FFFu + ((u >> 16) & 1u)) >> 16;  // round-to-nearest-even
    return (short)r;
}

__device__ inline f32x4 mfma16x16x32(short8 a, short8 b, f32x4 c) {
    return __builtin_amdgcn_mfma_f32_16x16x32_bf16(a, b, c, 0, 0, 0);
}

// ---------------------------------------------------------------------------
// BT-GEMM: C[M,N] = A[M,KP] * B[N,KP]^T  (bf16, KP%32==0, M%256==0)
// MODE 0: full-K, += bias[col].  MODE 1: split-K partials to C + z*M*ldc.
// Block 256x128, 4 waves (2x2), wave tile 128x64. 3-slab LDS (72 KB ->
// 2 blocks/CU for cross-block phase overlap, the m114 mechanism).
// Per K-tile (BK=32) 2 phases:
//   P1: 8 ds_read (A mi0-3 + B) | stage A(t+2) | bar | lgkm(0) |
//       setprio(1) 16 MFMA setprio(0) | bar
//   P2: 4 ds_read (A mi4-7)     | stage B(t+2) | bar | lgkm(0) |
//       setprio(1) 16 MFMA setprio(0) | boundary vmcnt | bar
// Counted boundary vmcnt(6): t+1's 6 loads complete, t+2's 6 stay in flight;
// vmcnt(0) fallback when tail stages were skipped. Slab (t+2)%3 was last
// read in tile t-1 and drained at that tile's trailing barrier -> no race.
// 16B-block XOR swizzle on BOTH sides (global src + ds_read) -> 0 conflicts.
// ---------------------------------------------------------------------------
template <int MODE>
__global__ __launch_bounds__(256, 2) void gemm_bt(
    const short* __restrict__ A, const short* __restrict__ B,
    float* __restrict__ C, int M, int N, int KP, int ldc,
    const float* __restrict__ bias)
{
    __shared__ alignas(16) short As[3][256 * 32];
    __shared__ alignas(16) short Bs[3][128 * 32];

    const int tid = threadIdx.x;
    const int l   = tid & 63;
    const int w   = tid >> 6;
    const int wr  = w >> 1, wc = w & 1;
    const int m0  = blockIdx.x * 256;
    const int n0  = blockIdx.y * 128;

    int k_beg = 0, k_end = KP;
    if (MODE == 1) {
        int steps = KP >> 5;
        long long z = blockIdx.z;
        int s0 = (int)(z * steps / gridDim.z);
        int s1 = (int)((z + 1) * steps / gridDim.z);
        k_beg = s0 << 5;
        k_end = s1 << 5;
    }

    const int sr   = l >> 2;
    const int sc   = ((l & 3) ^ ((sr >> 1) & 3)) * 8;
    const int lr   = l & 15;
    const int kg   = l >> 4;
    const int kswz = (kg ^ ((lr >> 1) & 3)) * 8;

    const short* gaB[4];
#pragma unroll
    for (int i = 0; i < 4; ++i)
        gaB[i] = A + (size_t)(m0 + (w * 4 + i) * 16 + sr) * KP + sc;
    const short* gbB[2];
#pragma unroll
    for (int i = 0; i < 2; ++i) {
        int rB = n0 + (w * 2 + i) * 16 + sr;
        if (rB > N - 1) rB = N - 1;
        gbB[i] = B + (size_t)rB * KP + sc;
    }

    auto stageA = [&](int buf, int k0) {
#pragma unroll
        for (int i = 0; i < 4; ++i)
            __builtin_amdgcn_global_load_lds(
                (const __attribute__((address_space(1))) void*)(gaB[i] + k0),
                (__attribute__((address_space(3))) void*)(&As[buf][(w * 4 + i) * 512]), 16, 0, 0);
    };
    auto stageB = [&](int buf, int k0) {
#pragma unroll
        for (int i = 0; i < 2; ++i)
            __builtin_amdgcn_global_load_lds(
                (const __attribute__((address_space(1))) void*)(gbB[i] + k0),
                (__attribute__((address_space(3))) void*)(&Bs[buf][(w * 2 + i) * 512]), 16, 0, 0);
    };

    f32x4 acc[8][4] = {};

    const int nt = (k_end - k_beg) >> 5;
    stageA(0, k_beg); stageB(0, k_beg);
    if (nt > 1) { stageA(1, k_beg + 32); stageB(1, k_beg + 32); }
    if (nt > 1) { asm volatile("s_waitcnt vmcnt(6)" ::: "memory"); }
    else        { asm volatile("s_waitcnt vmcnt(0)" ::: "memory"); }
    __builtin_amdgcn_s_barrier();
    __builtin_amdgcn_sched_barrier(0);

    int rd = 0;
    for (int t = 0; t < nt; ++t) {
        int wb = rd + 2; if (wb >= 3) wb -= 3;
        const int kpre = k_beg + ((t + 2) << 5);
        const short* Ar = &As[rd][0];
        const short* Br = &Bs[rd][0];
        short8 af[4], bf[4], af2[4];

        // ---- P1: A mi0-3 + B frags; prefetch A(t+2)
#pragma unroll
        for (int mi = 0; mi < 4; ++mi)
            af[mi] = *(const short8*)&Ar[(wr * 128 + mi * 16 + lr) * 32 + kswz];
#pragma unroll
        for (int ni = 0; ni < 4; ++ni)
            bf[ni] = *(const short8*)&Br[(wc * 64 + ni * 16 + lr) * 32 + kswz];
        if (t + 2 < nt) stageA(wb, kpre);
        __builtin_amdgcn_s_barrier();
        asm volatile("s_waitcnt lgkmcnt(0)" ::: "memory");
        __builtin_amdgcn_sched_barrier(0);
        __builtin_amdgcn_s_setprio(1);
#pragma unroll
        for (int mi = 0; mi < 4; ++mi)
#pragma unroll
            for (int ni = 0; ni < 4; ++ni)
                acc[mi][ni] = mfma16x16x32(af[mi], bf[ni], acc[mi][ni]);
        __builtin_amdgcn_s_setprio(0);
        __builtin_amdgcn_sched_barrier(0);
        __builtin_amdgcn_s_barrier();
        __builtin_amdgcn_sched_barrier(0);

        // ---- P2: A mi4-7 (bf reused); prefetch B(t+2)
#pragma unroll
        for (int mi = 0; mi < 4; ++mi)
            af2[mi] = *(const short8*)&Ar[(wr * 128 + (mi + 4) * 16 + lr) * 32 + kswz];
        if (t + 2 < nt) stageB(wb, kpre);
        __builtin_amdgcn_s_barrier();
        asm volatile("s_waitcnt lgkmcnt(0)" ::: "memory");
        __builtin_amdgcn_sched_barrier(0);
        __builtin_amdgcn_s_setprio(1);
#pragma unroll
        for (int mi = 0; mi < 4; ++mi)
#pragma unroll
            for (int ni = 0; ni < 4; ++ni)
                acc[mi + 4][ni] = mfma16x16x32(af2[mi], bf[ni], acc[mi + 4][ni]);
        __builtin_amdgcn_s_setprio(0);
        __builtin_amdgcn_sched_barrier(0);
        if (t + 2 < nt) { asm volatile("s_waitcnt vmcnt(6)" ::: "memory"); }
        else            { asm volatile("s_waitcnt vmcnt(0)" ::: "memory"); }
        __builtin_amdgcn_s_barrier();
        __builtin_amdgcn_sched_barrier(0);

        if (++rd == 3) rd = 0;
    }

    float* Cb = C;
    if (MODE == 1) Cb = C + (size_t)blockIdx.z * M * ldc;

#pragma unroll
    for (int ni = 0; ni < 4; ++ni) {
        int col = n0 + wc * 64 + ni * 16 + lr;
        if (col >= N) continue;
        float bv = (MODE == 0 && bias) ? bias[col] : 0.0f;
#pragma unroll
        for (int mi = 0; mi < 8; ++mi) {
            int row0 = m0 + wr * 128 + mi * 16 + kg * 4;
#pragma unroll
            for (int r = 0; r < 4; ++r)
                Cb[(size_t)(row0 + r) * ldc + col] = acc[mi][ni][r] + bv;
        }
    }
}

// ---------------------------------------------------------------------------
// fused gathers: entity row + BN0 -> f32 x[2048,400]; relation row -> bf16
// padded to 416 cols
// ---------------------------------------------------------------------------
__global__ void gather_fused(const float* __restrict__ E, const int* __restrict__ eidx,
                             const float* __restrict__ R, const int* __restrict__ ridx,
                             const float* g, const float* bb, const float* m,
                             const float* v, float* __restrict__ xout,
                             short* __restrict__ rout)
{
    int b = blockIdx.x;
    int e = eidx[b];
    float s = g[0] * rsqrtf(v[0] + EPSF);
    float t = bb[0] - m[0] * s;
    const float4* src = (const float4*)(E + (size_t)e * 400);
    float4* dst = (float4*)(xout + (size_t)b * 400);
    for (int i = threadIdx.x; i < 100; i += blockDim.x) {
        float4 u = src[i];
        dst[i] = make_float4(u.x * s + t, u.y * s + t, u.z * s + t, u.w * s + t);
    }
    int r = ridx[b];
    const float* rsrc = R + (size_t)r * 400;
    short* rdst = rout + (size_t)b * 416;
    for (int i = threadIdx.x; i < 416; i += blockDim.x)
        rdst[i] = (i < 400) ? f2bf(rsrc[i]) : (short)0;
}

// fc_w (400 x 37632) f32 -> bf16, same layout
__global__ void cvt_fcw(const float* __restrict__ in, short* __restrict__ out, int n4)
{
    int i = blockIdx.x * blockDim.x + threadIdx.x;
    int stride = gridDim.x * blockDim.x;
    const float4* in4 = (const float4*)in;
    short4* out4 = (short4*)out;
    for (; i < n4; i += stride) {
        float4 v = in4[i];
        out4[i] = make_short4(f2bf(v.x), f2bf(v.y), f2bf(v.z), f2bf(v.w));
    }
}

// fc1_w (864 x 400) f32 -> bf16 padded to ld 416
__global__ void cvt_fc1w_pad(const float* __restrict__ in, short* __restrict__ out)
{
    int i = blockIdx.x * blockDim.x + threadIdx.x;
    if (i >= 864 * 416) return;
    int row = i / 416, col = i - row * 416;
    out[i] = (col < 400) ? f2bf(in[row * 400 + col]) : (short)0;
}

// ---------------------------------------------------------------------------
// per-sample conv (96 out-ch, 9 taps, valid) + BN1 -> bf16 flat[b, o*392+l]
// ---------------------------------------------------------------------------
__global__ __launch_bounds__(256) void conv_bn1(
    const float* __restrict__ xall, const float* __restrict__ kfall,
    const float* __restrict__ g1, const float* __restrict__ b1,
    const float* __restrict__ m1, const float* __restrict__ v1,
    short* __restrict__ flat, int b_base)
{
    __shared__ float xs[400];
    __shared__ float ks[864];
    __shared__ float s1s[96], t1s[96];
    const int b = b_base + blockIdx.x;
    const int tid = threadIdx.x;
    const float* xr = xall + (size_t)b * 400;
    const float* kr = kfall + (size_t)b * 864;
    for (int i = tid; i < 400; i += 256) xs[i] = xr[i];
    for (int i = tid; i < 864; i += 256) ks[i] = kr[i];
    if (tid < 96) {
        float s = g1[tid] * rsqrtf(v1[tid] + EPSF);
        s1s[tid] = s;
        t1s[tid] = b1[tid] - m1[tid] * s;
    }
    __syncthreads();
    short8* fr8 = (short8*)(flat + (size_t)blockIdx.x * 37632);
    for (int i = tid; i < 4704; i += 256) {
        int o   = i / 49;
        int ll0 = (i - o * 49) * 8;
        const float* kk = &ks[o * 9];
        float xv[16];
        const float4* xp = (const float4*)&xs[ll0];
#pragma unroll
        for (int q = 0; q < 4; ++q) {
            float4 u = xp[q];
            xv[q * 4 + 0] = u.x; xv[q * 4 + 1] = u.y;
            xv[q * 4 + 2] = u.z; xv[q * 4 + 3] = u.w;
        }
        float s1 = s1s[o], t1 = t1s[o];
        short8 outv;
#pragma unroll
        for (int j = 0; j < 8; ++j) {
            float a = 0.f;
#pragma unroll
            for (int f = 0; f < 9; ++f) a += xv[j + f] * kk[f];
            outv[j] = f2bf(a * s1 + t1);
        }
        fr8[i] = outv;
    }
}

// sum NZ split-K partials + fc_b + BN2 + ReLU -> bf16 x_out rows, ld 416 (pad=0)
__global__ void reduce_bn2(const float* __restrict__ hp, int C, int nz,
                           const float* __restrict__ fcb,
                           const float* __restrict__ g2, const float* __restrict__ b2,
                           const float* __restrict__ m2, const float* __restrict__ v2,
                           short* __restrict__ xout, int cb)
{
    int i = blockIdx.x * blockDim.x + threadIdx.x;
    int total = C * 416;
    if (i >= total) return;
    int row = i / 416, col = i - row * 416;
    short val = 0;
    if (col < 400) {
        float s = 0.f;
        size_t stride = (size_t)C * 400;
        size_t basei = (size_t)row * 400 + col;
        for (int k = 0; k < nz; ++k) s += hp[k * stride + basei];
        float sc = g2[col] * rsqrtf(v2[col] + EPSF);
        float hv = (s + fcb[col] - m2[col]) * sc + b2[col];
        val = f2bf(fmaxf(hv, 0.f));
    }
    xout[(size_t)(cb + row) * 416 + col] = val;
}

extern "C" void kernel_launch(void* const* d_in, const int* in_sizes, int n_in,
                              void* d_out, int out_size, void* d_ws, size_t ws_size,
                              hipStream_t stream)
{
    (void)in_sizes; (void)n_in; (void)out_size;
    const int*   e1    = (const int*)d_in[0];
    const int*   r1i   = (const int*)d_in[1];
    const int*   r2i   = (const int*)d_in[2];
    const int*   e2    = (const int*)d_in[3];
    const float* E_w   = (const float*)d_in[4];
    const float* R_w   = (const float*)d_in[5];
    const float* fc1_w = (const float*)d_in[6];
    const float* fc1_b = (const float*)d_in[7];
    const float* fc_w  = (const float*)d_in[8];
    const float* fc_b  = (const float*)d_in[9];
    const float* bn0_g = (const float*)d_in[10];
    const float* bn0_b = (const float*)d_in[11];
    const float* bn0_m = (const float*)d_in[12];
    const float* bn0_v = (const float*)d_in[13];
    const float* bn1_g = (const float*)d_in[14];
    const float* bn1_b = (const float*)d_in[15];
    const float* bn1_m = (const float*)d_in[16];
    const float* bn1_v = (const float*)d_in[17];
    const float* bn2_g = (const float*)d_in[18];
    const float* bn2_b = (const float*)d_in[19];
    const float* bn2_m = (const float*)d_in[20];
    const float* bn2_v = (const float*)d_in[21];
    const float* bbias = (const float*)d_in[22];
    float* out = (float*)d_out;

    char* basep = (char*)d_ws;
    size_t off = 0;
    auto alloc = [&](size_t bytes) -> char* {
        char* p = basep + off;
        off = (off + bytes + 255) & ~(size_t)255;
        return p;
    };
    short* fcw_b  = (short*)alloc(400ULL * 37632 * 2);
    short* fc1w_b = (short*)alloc(864ULL * 416 * 2);
    float* xf     = (float*)alloc(2048ULL * 400 * 4);
    short* rb     = (short*)alloc(2048ULL * 416 * 2);
    float* kf     = (float*)alloc(2048ULL * 864 * 4);
    short* x1b    = (short*)alloc(2048ULL * 416 * 2);
    short* x2b    = (short*)alloc(2048ULL * 416 * 2);
    size_t fixed = off;

    const int NZ = 16;  // split-K ways: grid 8x4x16 = 512 = 2 blocks/CU
    int CHUNK = 256;
    for (int c = 2048; c >= 256; c >>= 1) {
        size_t need = fixed + ((size_t)c * 400 * NZ * 4 + 256) + ((size_t)c * 37632 * 2 + 256);
        if (need <= ws_size) { CHUNK = c; break; }
    }
    float* hpart = (float*)alloc((size_t)CHUNK * 400 * NZ * 4);
    short* flat  = (short*)alloc((size_t)CHUNK * 37632 * 2);

    // weights -> bf16 (recomputed each call; deterministic)
    cvt_fcw<<<2048, 256, 0, stream>>>(fc_w, fcw_b, 400 * 37632 / 4);
    cvt_fc1w_pad<<<(864 * 416 + 255) / 256, 256, 0, stream>>>(fc1_w, fc1w_b);

    for (int br = 0; br < 2; ++br) {
        const int* eidx = (br == 0) ? e1 : e2;
        const int* ridx = (br == 0) ? r1i : r2i;
        short* xob = (br == 0) ? x1b : x2b;

        gather_fused<<<2048, 128, 0, stream>>>(E_w, eidx, R_w, ridx,
                                               bn0_g, bn0_b, bn0_m, bn0_v, xf, rb);
        // k filters: (2048x400) @ (864x400)^T + fc1_b -> f32 (2048x864)
        gemm_bt<0><<<dim3(8, 7), 256, 0, stream>>>(rb, fc1w_b, kf, 2048, 864, 416, 864, fc1_b);

        for (int cb = 0; cb < 2048; cb += CHUNK) {
            conv_bn1<<<CHUNK, 256, 0, stream>>>(xf, kf, bn1_g, bn1_b, bn1_m, bn1_v, flat, cb);
            // fc: (CHUNK x 37632) @ (400 x 37632)^T, split-K x NZ partials
            gemm_bt<1><<<dim3(CHUNK / 256, 4, NZ), 256, 0, stream>>>(
                flat, fcw_b, hpart, CHUNK, 400, 37632, 400, nullptr);
            reduce_bn2<<<(CHUNK * 416 + 255) / 256, 256, 0, stream>>>(
                hpart, CHUNK, NZ, fc_b, bn2_g, bn2_b, bn2_m, bn2_v, xob, cb);
        }
    }

    // logits = x1 @ x2^T + b_bias[col]  -> f32 (2048x2048)
    gemm_bt<0><<<dim3(8, 16), 256, 0, stream>>>(x1b, x2b, out, 2048, 2048, 416, 2048, bbias);
}